// Round 1
// 1092.352 us; speedup vs baseline: 1.1620x; 1.1620x over previous
//
#include <hip/hip_runtime.h>
#include <stdint.h>

typedef short short8 __attribute__((ext_vector_type(8)));
typedef float f32x4 __attribute__((ext_vector_type(4)));
typedef unsigned short u16;

#define HID 256
#define NLAYERS 5
#define BN_EPS 1e-5f

__device__ __forceinline__ float bf2f(u16 u) {
    union { unsigned int i; float f; } v;
    v.i = ((unsigned int)u) << 16;
    return v.f;
}
__device__ __forceinline__ u16 f2bf(float f) {
    union { float f; unsigned int i; } v;
    v.f = f;
    unsigned int r = v.i + 0x7FFFu + ((v.i >> 16) & 1u);   // RNE
    return (u16)(r >> 16);
}
// split fp32 -> (hi, lo) bf16 pair: hi+lo ~ 17-bit mantissa approximation
__device__ __forceinline__ void split_bf(float f, u16& hi, u16& lo) {
    hi = f2bf(f);
    lo = f2bf(f - bf2f(hi));
}

// 16-B direct global->LDS copy (vmcnt-tracked; drained by __syncthreads).
__device__ __forceinline__ void gl_lds16(const void* gsrc, void* ldst) {
    const __attribute__((address_space(1))) unsigned int* g =
        reinterpret_cast<const __attribute__((address_space(1))) unsigned int*>(
            reinterpret_cast<uintptr_t>(gsrc));
    __attribute__((address_space(3))) unsigned int* l =
        reinterpret_cast<__attribute__((address_space(3))) unsigned int*>(
            reinterpret_cast<uintptr_t>(ldst));
    __builtin_amdgcn_global_load_lds(g, l, 16, 0, 0);
}

// ---------------- utility ----------------

__global__ __launch_bounds__(256) void k_zero32(unsigned int* p, int n) {
    int i = blockIdx.x * 256 + threadIdx.x;
    if (i < n) p[i] = 0u;
}

// ---------------- graph preprocessing (staged in d_out) ----------------

__global__ __launch_bounds__(256) void k_detect(const int* ei, int* flag, int E) {
    __shared__ int nz;
    if (threadIdx.x == 0) nz = 0;
    __syncthreads();
    int lim = (2 * E < 4096) ? 2 * E : 4096;
    int c = 0;
    for (int i = threadIdx.x; 2 * i + 1 < lim; i += 256) c += (ei[2 * i + 1] != 0);
    atomicAdd(&nz, c);
    __syncthreads();
    if (threadIdx.x == 0) flag[0] = (nz == 0) ? 1 : 0;   // 1 => int64 layout
}

__global__ __launch_bounds__(256) void k_deg(const int* ei, const int* flag, int* deg, int E, int N) {
    int e = blockIdx.x * 256 + threadIdx.x;
    if (e >= E) return;
    int w = flag[0];
    int col = w ? ei[2 * (E + e)] : ei[E + e];
    if ((unsigned)col < (unsigned)N) atomicAdd(&deg[col], 1);
}

__global__ __launch_bounds__(256) void k_dinv(const int* deg, float* dinv, int N) {
    int n = blockIdx.x * 256 + threadIdx.x;
    if (n < N) { int d = deg[n]; dinv[n] = d > 0 ? rsqrtf((float)d) : 0.0f; }
}

__global__ __launch_bounds__(256) void k_scan1(const int* deg, int* offs, int* bsum, int N) {
    __shared__ int s[256];
    int tid = threadIdx.x;
    int i = blockIdx.x * 256 + tid;
    int v = (i < N) ? deg[i] : 0;
    s[tid] = v;
    __syncthreads();
    for (int off = 1; off < 256; off <<= 1) {
        int t = (tid >= off) ? s[tid - off] : 0;
        __syncthreads();
        s[tid] += t;
        __syncthreads();
    }
    if (i < N) offs[i] = s[tid] - v;
    if (tid == 255) bsum[blockIdx.x] = s[tid];
}

__global__ __launch_bounds__(256) void k_scan2(const int* bsum, int* bscan, int NB) {
    __shared__ int s[256];
    int tid = threadIdx.x;
    int v = (tid < NB) ? bsum[tid] : 0;
    s[tid] = v;
    __syncthreads();
    for (int off = 1; off < 256; off <<= 1) {
        int t = (tid >= off) ? s[tid - off] : 0;
        __syncthreads();
        s[tid] += t;
        __syncthreads();
    }
    bscan[tid] = s[tid] - v;
}

__global__ __launch_bounds__(256) void k_scan3(int* offs, const int* bscan, int* cursor, int N, int E) {
    int i = blockIdx.x * 256 + threadIdx.x;
    if (i < N) {
        int o = offs[i] + bscan[blockIdx.x];
        offs[i] = o;
        cursor[i] = o;
    }
    if (i == 0) offs[N] = E;
}

__global__ __launch_bounds__(256) void k_place(const int* ei, const int* flag, const float4* eattr,
                                               int* cursor, int* srow, float4* sea, int E, int N) {
    int e = blockIdx.x * 256 + threadIdx.x;
    if (e >= E) return;
    int w = flag[0];
    int r = w ? ei[2 * e] : ei[e];
    int c = w ? ei[2 * (E + e)] : ei[E + e];
    if ((unsigned)c >= (unsigned)N) return;
    int p = atomicAdd(&cursor[c], 1);
    srow[p] = r;
    sea[p] = eattr[e];
}

__global__ __launch_bounds__(256) void k_move(const int* srow, const float4* sea, const float* sdinv,
                                              const int* soffs, int* rowArr, float4* eaP,
                                              float* dinvF, int* offsF, int E, int N) {
    int i = blockIdx.x * 256 + threadIdx.x;
    if (i < E) { rowArr[i] = srow[i]; eaP[i] = sea[i]; }
    if (i < N) dinvF[i] = sdinv[i];
    if (i <= N) offsF[i] = soffs[i];
}

__global__ __launch_bounds__(256) void k_precheckN(const int* offsF, const int* cursor, const float* dinvF,
                                                   const int* gflag, int* diag, int N, int E) {
    int i = blockIdx.x * 256 + threadIdx.x;
    if (i < N) {
        if (offsF[i + 1] < offsF[i]) atomicOr(&diag[0], 1);
        if (cursor[i] != offsF[i + 1]) atomicOr(&diag[0], 2);
        float d = dinvF[i];
        if (!(d == d) || fabsf(d) > 1e10f) atomicOr(&diag[0], 4);
    }
    if (i == 0) {
        if (offsF[N] != E) atomicOr(&diag[0], 8);
        diag[7] = gflag[0];
    }
}
__global__ __launch_bounds__(256) void k_precheckE(const int* rowArr, int* diag, int E, int N) {
    int p = blockIdx.x * 256 + threadIdx.x;
    if (p < E && (unsigned)rowArr[p] >= (unsigned)N) atomicOr(&diag[0], 16);
}

// Per-layer: split W (fp32 512x256 row-major) into bf16 hi/lo planes in MFMA
// B-fragment order, kb-major: frag t = kb*1024 + nbg*64 + lane holds
// W[kb*32 + (lane>>4)*8 + j][nbg*16 + (lane&15)], j=0..7.
// Block 0 also zeroes the BN stats accumulators (512 floats at colsum).
__global__ __launch_bounds__(256) void k_wsplit(const float* W, u16* wpH, u16* wpL, float* colsum) {
    if (blockIdx.x == 0) {
        colsum[threadIdx.x] = 0.f;
        colsum[256 + threadIdx.x] = 0.f;
    }
    int t = blockIdx.x * 256 + threadIdx.x;   // 64 blocks -> 16384 frags
    int lane = t & 63;
    int nbg = (t >> 6) & 15;
    int kb = t >> 10;
    int quad = lane >> 4, nl = lane & 15;
    const float* src = W + (size_t)(kb * 32 + quad * 8) * HID + nbg * 16 + nl;
    short8 vh, vl;
#pragma unroll
    for (int j = 0; j < 8; ++j) {
        u16 h, l;
        split_bf(src[(size_t)j * HID], h, l);
        vh[j] = (short)h;
        vl[j] = (short)l;
    }
    *((short8*)wpH + t) = vh;
    *((short8*)wpL + t) = vl;
}

// ---------------- per-layer: aggregation (one wave per node), split output ----------------
__global__ __launch_bounds__(256) void k_agg(const void* hin_, const u16* hin_lo, int hf32,
                                             const int* offs, const int* rowArr, const float4* eaP,
                                             const float* dinv, const float* ew1, const float* ew2,
                                             u16* agg_hi, u16* agg_lo, int* diag, int M) {
    int lane = threadIdx.x & 63, wave = threadIdx.x >> 6;
    int n = blockIdx.x * 4 + wave;

    float w1v[4] = {0.f, 0.f, 0.f, 0.f};
    float w20[4] = {0.f, 0.f, 0.f, 0.f};
    float w21[4] = {0.f, 0.f, 0.f, 0.f};
    float w22[4] = {0.f, 0.f, 0.f, 0.f};
    if (lane < 32) {
        int c = lane * 4;
#pragma unroll
        for (int j = 0; j < 4; ++j) w1v[j] = ew1[c + j];
    } else {
        int cc = (lane - 32) * 4;
#pragma unroll
        for (int j = 0; j < 4; ++j) {
            w20[j] = ew2[cc + j];
            w21[j] = ew2[128 + cc + j];
            w22[j] = ew2[256 + cc + j];
        }
    }

    if (n >= M) return;
    float dn = dinv[n];
    int s = offs[n], e = offs[n + 1];
    float a0 = 0.f, a1 = 0.f, a2 = 0.f, a3 = 0.f;
    for (int p = s; p < e; ++p) {
        int r = rowArr[p];
        float4 ea = eaP[p];
        float nrm = dn * dinv[r];
        float h0, h1, h2, h3;
        if (hf32) {
            float4 hv = *((const float4*)hin_ + (size_t)r * 64 + lane);
            h0 = hv.x; h1 = hv.y; h2 = hv.z; h3 = hv.w;
        } else {
            ushort4 hh = *((const ushort4*)hin_ + (size_t)r * 64 + lane);
            ushort4 hl = *((const ushort4*)hin_lo + (size_t)r * 64 + lane);
            h0 = bf2f(hh.x) + bf2f(hl.x);
            h1 = bf2f(hh.y) + bf2f(hl.y);
            h2 = bf2f(hh.z) + bf2f(hl.z);
            h3 = bf2f(hh.w) + bf2f(hl.w);
        }
        a0 += nrm * (h0 + ea.w * w1v[0] + ea.x * w20[0] + ea.y * w21[0] + ea.z * w22[0]);
        a1 += nrm * (h1 + ea.w * w1v[1] + ea.x * w20[1] + ea.y * w21[1] + ea.z * w22[1]);
        a2 += nrm * (h2 + ea.w * w1v[2] + ea.x * w20[2] + ea.y * w21[2] + ea.z * w22[2]);
        a3 += nrm * (h3 + ea.w * w1v[3] + ea.x * w20[3] + ea.y * w21[3] + ea.z * w22[3]);
    }
    int bad = 0;
    if (!(a0 == a0)) { a0 = 777.f; bad++; }
    if (!(a1 == a1)) { a1 = 777.f; bad++; }
    if (!(a2 == a2)) { a2 = 777.f; bad++; }
    if (!(a3 == a3)) { a3 = 777.f; bad++; }
    if (bad) atomicAdd(&diag[1], bad);
    ushort4 oh, ol;
    split_bf(a0, oh.x, ol.x);
    split_bf(a1, oh.y, ol.y);
    split_bf(a2, oh.z, ol.z);
    split_bf(a3, oh.w, ol.w);
    *((ushort4*)agg_hi + (size_t)n * 64 + lane) = oh;
    *((ushort4*)agg_lo + (size_t)n * 64 + lane) = ol;
}

// ---------------- per-layer: split-precision MFMA GEMM + bias/ReLU + BN stats ----------------
// y = relu(A·W + bias); A = [h | agg] as bf16 hi/lo pairs (fp32 x split on the fly at l0).
// acc = Ahi·Whi + Alo·Whi + Ahi·Wlo.
// NEW structure (v2): 128 rows x 256 cols per block, 4 waves x 2 row-groups (acc 128 VGPR,
// 2x register B-reuse). Per K-step (BK=32) the 32 KB B kb-slice (hi+lo, fragment-linear
// from k_wsplit) is staged into LDS once per BLOCK via global_load_lds width-16
// (was: every WAVE streamed all 512 KB of W from L2 -> latency-bound, MfmaUtil 12%).
// 2-barrier loop (m97 structure); B frags via contiguous conflict-free ds_read_b128.
__global__ __launch_bounds__(256, 2) void MPNN_79044578115931_kernel(
        const void* hinA_, const u16* hinA_lo, int hf32,
        const u16* agg_hi, const u16* agg_lo,
        const u16* wpH, const u16* wpL, const float* bias,
        u16* y_hi, u16* y_lo,
        float* colsum, float* colsumsq, int* diag, int M) {
    __shared__ __align__(16) u16 bstage[16384];   // 32 KB: hi frags [0,8192), lo frags [8192,16384)
    __shared__ float lsum[256];
    __shared__ float lsq[256];

    int tid = threadIdx.x;
    int lane = tid & 63, wave = tid >> 6;
    int quad = lane >> 4, nl = lane & 15;
    int mBase = blockIdx.x * 128 + wave * 32;
    int rowA0 = mBase + nl;          // row-group 0
    int rowA1 = mBase + 16 + nl;     // row-group 1
    if (rowA0 >= M) rowA0 = M - 1;
    if (rowA1 >= M) rowA1 = M - 1;

    lsum[tid] = 0.f;
    lsq[tid] = 0.f;

    f32x4 acc0[16], acc1[16];
#pragma unroll
    for (int i = 0; i < 16; ++i) {
        acc0[i] = {0.f, 0.f, 0.f, 0.f};
        acc1[i] = {0.f, 0.f, 0.f, 0.f};
    }

    for (int kb = 0; kb < 16; ++kb) {
        __syncthreads();   // previous K-step's LDS reads done before overwrite

        // stage B kb-slice: 2048 frags x 16 B, thread t handles frags {i*256+t}
        const u16* srcH = wpH + (size_t)kb * 8192;
        const u16* srcL = wpL + (size_t)kb * 8192;
#pragma unroll
        for (int i = 0; i < 4; ++i) {
            int ci = i * 256 + tid;
            gl_lds16(srcH + ci * 8, &bstage[ci * 8]);
            gl_lds16(srcL + ci * 8, &bstage[8192 + ci * 8]);
        }

        // A fragments for this K-step (latency covered by the drain barrier below)
        short8 a0h, a0l, a1h, a1l;
        if (kb < 8) {
            int k0 = kb * 32 + quad * 8;
            if (hf32) {
                const float* hp0 = (const float*)hinA_ + (size_t)rowA0 * HID + k0;
                const float* hp1 = (const float*)hinA_ + (size_t)rowA1 * HID + k0;
#pragma unroll
                for (int j = 0; j < 8; ++j) {
                    u16 h, l;
                    split_bf(hp0[j], h, l);
                    a0h[j] = (short)h; a0l[j] = (short)l;
                    split_bf(hp1[j], h, l);
                    a1h[j] = (short)h; a1l[j] = (short)l;
                }
            } else {
                a0h = *(const short8*)((const u16*)hinA_ + (size_t)rowA0 * HID + k0);
                a0l = *(const short8*)(hinA_lo + (size_t)rowA0 * HID + k0);
                a1h = *(const short8*)((const u16*)hinA_ + (size_t)rowA1 * HID + k0);
                a1l = *(const short8*)(hinA_lo + (size_t)rowA1 * HID + k0);
            }
        } else {
            int k0 = (kb - 8) * 32 + quad * 8;
            a0h = *(const short8*)(agg_hi + (size_t)rowA0 * HID + k0);
            a0l = *(const short8*)(agg_lo + (size_t)rowA0 * HID + k0);
            a1h = *(const short8*)(agg_hi + (size_t)rowA1 * HID + k0);
            a1l = *(const short8*)(agg_lo + (size_t)rowA1 * HID + k0);
        }

        __syncthreads();   // drains vmcnt(0): staged B + A frags ready

        const short8* bbase = (const short8*)bstage;
#pragma unroll
        for (int nbg = 0; nbg < 16; ++nbg) {
            short8 bh = bbase[nbg * 64 + lane];
            short8 bl = bbase[1024 + nbg * 64 + lane];
            acc0[nbg] = __builtin_amdgcn_mfma_f32_16x16x32_bf16(a0h, bh, acc0[nbg], 0, 0, 0);
            acc1[nbg] = __builtin_amdgcn_mfma_f32_16x16x32_bf16(a1h, bh, acc1[nbg], 0, 0, 0);
            acc0[nbg] = __builtin_amdgcn_mfma_f32_16x16x32_bf16(a0l, bh, acc0[nbg], 0, 0, 0);
            acc1[nbg] = __builtin_amdgcn_mfma_f32_16x16x32_bf16(a1l, bh, acc1[nbg], 0, 0, 0);
            acc0[nbg] = __builtin_amdgcn_mfma_f32_16x16x32_bf16(a0h, bl, acc0[nbg], 0, 0, 0);
            acc1[nbg] = __builtin_amdgcn_mfma_f32_16x16x32_bf16(a1h, bl, acc1[nbg], 0, 0, 0);
        }
    }

    // epilogue: bias + ReLU + split-store + BN partial stats (pre-split fp32)
    int badY = 0;
#pragma unroll
    for (int nbg = 0; nbg < 16; ++nbg) {
        int c = nbg * 16 + nl;
        float bv = bias[c];
        float s = 0.f, q = 0.f;
#pragma unroll
        for (int r = 0; r < 4; ++r) {
            int m = mBase + quad * 4 + r;
            if (m < M) {
                float v = acc0[nbg][r] + bv;
                if (!(v == v)) { v = 777.f; badY++; }
                v = v > 0.f ? v : 0.f;
                u16 h, l;
                split_bf(v, h, l);
                y_hi[(size_t)m * HID + c] = h;
                y_lo[(size_t)m * HID + c] = l;
                s += v;
                q += v * v;
            }
        }
        atomicAdd(&lsum[c], s);
        atomicAdd(&lsq[c], q);
    }
#pragma unroll
    for (int nbg = 0; nbg < 16; ++nbg) {
        int c = nbg * 16 + nl;
        float bv = bias[c];
        float s = 0.f, q = 0.f;
#pragma unroll
        for (int r = 0; r < 4; ++r) {
            int m = mBase + 16 + quad * 4 + r;
            if (m < M) {
                float v = acc1[nbg][r] + bv;
                if (!(v == v)) { v = 777.f; badY++; }
                v = v > 0.f ? v : 0.f;
                u16 h, l;
                split_bf(v, h, l);
                y_hi[(size_t)m * HID + c] = h;
                y_lo[(size_t)m * HID + c] = l;
                s += v;
                q += v * v;
            }
        }
        atomicAdd(&lsum[c], s);
        atomicAdd(&lsq[c], q);
    }
    if (badY) atomicAdd(&diag[2], badY);
    __syncthreads();
    atomicAdd(&colsum[tid], lsum[tid]);
    atomicAdd(&colsumsq[tid], lsq[tid]);
}

__global__ __launch_bounds__(256) void k_bnscale(const float* colsum, const float* colsumsq,
                                                 const float* g, const float* b,
                                                 float* scale, float* shift, int* diag, int M) {
    int c = threadIdx.x;
    float mu = colsum[c] / (float)M;
    float var = colsumsq[c] / (float)M - mu * mu;
    if (!(mu == mu) || !(var == var) || var > 1e30f) atomicAdd(&diag[3], 1);
    if (var < 0.f) var = 0.f;
    float sc = rsqrtf(var + BN_EPS) * g[c];
    scale[c] = sc;
    shift[c] = b[c] - mu * sc;
}

// BN apply: non-final = in-place on hi/lo planes (+ReLU); final = write fp32 to outf.
__global__ __launch_bounds__(256) void k_bnapply(u16* y_hi, u16* y_lo,
                                                 const float* scale, const float* shift,
                                                 float* outf, int finalL, int relu, int total) {
    int q4 = blockIdx.x * 256 + threadIdx.x;
    int idx = q4 * 4;
    if (idx >= total) return;
    int c = idx & (HID - 1);
    ushort4 vh = *((const ushort4*)y_hi + q4);
    ushort4 vl = *((const ushort4*)y_lo + q4);
    float o0 = scale[c + 0] * (bf2f(vh.x) + bf2f(vl.x)) + shift[c + 0];
    float o1 = scale[c + 1] * (bf2f(vh.y) + bf2f(vl.y)) + shift[c + 1];
    float o2 = scale[c + 2] * (bf2f(vh.z) + bf2f(vl.z)) + shift[c + 2];
    float o3 = scale[c + 3] * (bf2f(vh.w) + bf2f(vl.w)) + shift[c + 3];
    if (relu) {
        o0 = o0 > 0.f ? o0 : 0.f;
        o1 = o1 > 0.f ? o1 : 0.f;
        o2 = o2 > 0.f ? o2 : 0.f;
        o3 = o3 > 0.f ? o3 : 0.f;
    }
    if (finalL) {
        float4 ov; ov.x = o0; ov.y = o1; ov.z = o2; ov.w = o3;
        *((float4*)outf + q4) = ov;
    } else {
        ushort4 oh, ol;
        split_bf(o0, oh.x, ol.x);
        split_bf(o1, oh.y, ol.y);
        split_bf(o2, oh.z, ol.z);
        split_bf(o3, oh.w, ol.w);
        *((ushort4*)y_hi + q4) = oh;
        *((ushort4*)y_lo + q4) = ol;
    }
}

// d_out[0] = (1+k+8*int64)*2^20 only if a check failed.
__global__ void k_encode(const int* diag, float* out) {
    if (threadIdx.x != 0 || blockIdx.x != 0) return;
    int k = -1;
    for (int i = 0; i < 4; ++i) if (diag[i] != 0) { k = i; break; }
    if (k < 0) return;
    out[0] = (float)(1 + k + (diag[7] != 0 ? 8 : 0)) * 1048576.0f;
}

// ---------------- launcher (zero workspace dependency) ----------------

extern "C" void kernel_launch(void* const* d_in, const int* in_sizes, int n_in,
                              void* d_out, int out_size, void* d_ws, size_t ws_size,
                              hipStream_t stream) {
    const float*  x     = (const float*)d_in[0];
    const int*    ei    = (const int*)d_in[1];
    const float4* eattr = (const float4*)d_in[2];
    const float*  mlp_w = (const float*)d_in[3];
    const float*  mlp_b = (const float*)d_in[4];
    const float*  ew1   = (const float*)d_in[5];
    const float*  ew2   = (const float*)d_in[6];
    const float*  bn_g  = (const float*)d_in[7];
    const float*  bn_b  = (const float*)d_in[8];
    (void)n_in; (void)out_size; (void)d_ws; (void)ws_size;

    const int N = in_sizes[0] / HID;   // 50000
    const int E = in_sizes[1] / 2;     // 320000
    const size_t P = (size_t)N * HID;  // plane elements

    // ---- CSR staging inside d_out (dead before layer 0 writes d_out) ----
    char* st = (char*)d_out;
    int*    S_deg    = (int*)   (st + 0);
    float*  S_dinv   = (float*) (st + 204800);
    int*    S_offs   = (int*)   (st + 409600);
    int*    S_cursor = (int*)   (st + 614400);
    int*    S_bsum   = (int*)   (st + 819200);
    int*    S_bscan  = (int*)   (st + 820224);
    int*    S_gflag  = (int*)   (st + 821248);
    int*    S_row    = (int*)   (st + 1048576);
    float4* S_ea     = (float4*)(st + 2621440);   // ends 7,741,440 < 51.2 MB

    // ---- small homes in edge_index buffer (>=2.56 MB); eattr buffer holds eaP ----
    char* eb = (char*)d_in[1];
    int*   rowArr = (int*)  (eb + 0);          // 1,280,000
    float* dinvF  = (float*)(eb + 1280000);    // 200,000
    int*   offsF  = (int*)  (eb + 1480000);    // 200,004
    float* colsum = (float*)(eb + 1680128);
    float* colsq  = (float*)(eb + 1681152);
    float* scaleF = (float*)(eb + 1682176);
    float* shiftF = (float*)(eb + 1683200);
    int*   diag   = (int*)  (eb + 1684224);    // 1 KB
    u16*   wpH    = (u16*)  (eb + 1685504);    // 256 KB -> ends 1,947,648
    u16*   wpL    = (u16*)  (eb + 1947648);    // 256 KB -> ends 2,209,792 <= 2,560,000
    float4* eaP   = (float4*)d_in[2];          // 5,120,000 exact

    // ---- h slots as bf16 hi/lo planes (each slot = 2 planes = 51.2 MB) ----
    u16* sX_hi = (u16*)d_in[0];          // x buffer (x consumed during layer 0)
    u16* sX_lo = sX_hi + P;
    u16* sD_hi = (u16*)d_out;
    u16* sD_lo = sD_hi + P;

    int NB  = (N + 255) / 256;
    int NBE = (E + 255) / 256;
    int NBG = (N + 127) / 128;    // 391 GEMM blocks (128 rows each)
    int NBA = (N + 3) / 4;        // 12500 agg blocks (one wave per node)
    int NBQ = (int)((P / 4 + 255) / 256);

    // ---- preprocessing ----
    k_detect<<<1, 256, 0, stream>>>(ei, S_gflag, E);
    k_zero32<<<NB, 256, 0, stream>>>((unsigned int*)S_deg, N);
    k_deg<<<NBE, 256, 0, stream>>>(ei, S_gflag, S_deg, E, N);
    k_dinv<<<NB, 256, 0, stream>>>(S_deg, S_dinv, N);
    k_scan1<<<NB, 256, 0, stream>>>(S_deg, S_offs, S_bsum, N);
    k_scan2<<<1, 256, 0, stream>>>(S_bsum, S_bscan, NB);
    k_scan3<<<NB, 256, 0, stream>>>(S_offs, S_bscan, S_cursor, N, E);
    k_place<<<NBE, 256, 0, stream>>>(ei, S_gflag, eattr, S_cursor, S_row, S_ea, E, N);
    k_move<<<NBE, 256, 0, stream>>>(S_row, S_ea, S_dinv, S_offs, rowArr, eaP, dinvF, offsF, E, N);
    k_zero32<<<1, 256, 0, stream>>>((unsigned int*)diag, 256);
    k_precheckN<<<NB, 256, 0, stream>>>(offsF, S_cursor, dinvF, S_gflag, diag, N, E);
    k_precheckE<<<NBE, 256, 0, stream>>>(rowArr, diag, E, N);

    // ---- layers: even l -> dst = D(d_out), odd l -> dst = X; agg planes live in dst ----
    for (int l = 0; l < NLAYERS; ++l) {
        int even = (l % 2 == 0);
        u16* dst_hi = even ? sD_hi : sX_hi;
        u16* dst_lo = even ? sD_lo : sX_lo;
        const void* hinA; const u16* hin_lo; int hf32;
        if (l == 0) { hinA = (const void*)x; hin_lo = 0; hf32 = 1; }
        else if (even) { hinA = (const void*)sX_hi; hin_lo = sX_lo; hf32 = 0; }
        else { hinA = (const void*)sD_hi; hin_lo = sD_lo; hf32 = 0; }

        k_wsplit<<<64, 256, 0, stream>>>(mlp_w + (size_t)l * 512 * HID, wpH, wpL, colsum);
        k_agg<<<NBA, 256, 0, stream>>>(hinA, hin_lo, hf32, offsF, rowArr, eaP, dinvF,
                                       ew1 + (size_t)l * 128, ew2 + (size_t)l * 384,
                                       dst_hi, dst_lo, diag, N);
        MPNN_79044578115931_kernel<<<NBG, 256, 0, stream>>>(
            hinA, hin_lo, hf32, dst_hi, dst_lo, wpH, wpL,
            mlp_b + (size_t)l * HID, dst_hi, dst_lo, colsum, colsq, diag, N);
        k_bnscale<<<1, 256, 0, stream>>>(colsum, colsq,
                                         bn_g + (size_t)l * HID, bn_b + (size_t)l * HID,
                                         scaleF, shiftF, diag, N);
        int finalL = (l == NLAYERS - 1) ? 1 : 0;
        int relu = finalL ? 0 : 1;
        // final: expand planes (in d_out) -> fp32 into X buffer, then copy back to d_out
        k_bnapply<<<NBQ, 256, 0, stream>>>(dst_hi, dst_lo, scaleF, shiftF,
                                           (float*)d_in[0], finalL, relu, (int)P);
    }

    hipMemcpyAsync(d_out, d_in[0], P * 4, hipMemcpyDeviceToDevice, stream);
    k_encode<<<1, 64, 0, stream>>>(diag, (float*)d_out);
}